// Round 7
// baseline (52.528 us; speedup 1.0000x reference)
//
#include <hip/hip_runtime.h>
#include <hip/hip_fp16.h>

#define DELTA 0.05f
#define EPS 1e-8f

union H2F { __half2 h; float f; };

// ---------------------------------------------------------------------------
// Precompute per-gaussian packed 32-B record (two float4s, 32-B aligned):
//   r0 = [mux f32, muy f32, muz f32, (S00,S01) half2]
//   r1 = [(S02,S11) half2, (S12,S22) half2, (color,0) half2, pad]
// ---------------------------------------------------------------------------
__global__ __launch_bounds__(256) void precompute_gauss(
    const float* __restrict__ mu,
    const float* __restrict__ scaling,
    const float* __restrict__ rot,
    const float* __restrict__ color,
    float4* __restrict__ table, int G)
{
    int g = blockIdx.x * blockDim.x + threadIdx.x;
    if (g >= G) return;
    float qw = rot[g*4+0], qx = rot[g*4+1], qy = rot[g*4+2], qz = rot[g*4+3];
    float inv_norm = rsqrtf(qw*qw + qx*qx + qy*qy + qz*qz + EPS);
    qw *= inv_norm; qx *= inv_norm; qy *= inv_norm; qz *= inv_norm;
    float x2 = qx*qx, y2 = qy*qy, z2 = qz*qz;
    float xy = qx*qy, xz = qx*qz, yz = qy*qz;
    float wx = qw*qx, wy = qw*qy, wz = qw*qz;
    float R00 = 1.f - 2.f*(y2 + z2), R01 = 2.f*(xy - wz),       R02 = 2.f*(xz + wy);
    float R10 = 2.f*(xy + wz),       R11 = 1.f - 2.f*(x2 + z2), R12 = 2.f*(yz - wx);
    float R20 = 2.f*(xz - wy),       R21 = 2.f*(yz + wx),       R22 = 1.f - 2.f*(x2 + y2);
    float s0 = scaling[g*3+0], s1 = scaling[g*3+1], s2 = scaling[g*3+2];
    float d0 = s0*s0, d1 = s1*s1, d2 = s2*s2;
    float S00 = R00*R00*d0 + R01*R01*d1 + R02*R02*d2;
    float S01 = R00*R10*d0 + R01*R11*d1 + R02*R12*d2;
    float S02 = R00*R20*d0 + R01*R21*d1 + R02*R22*d2;
    float S11 = R10*R10*d0 + R11*R11*d1 + R12*R12*d2;
    float S12 = R10*R20*d0 + R11*R21*d1 + R12*R22*d2;
    float S22 = R20*R20*d0 + R21*R21*d1 + R22*R22*d2;

    H2F u01, u21, u22, uc;
    u01.h = __floats2half2_rn(S00, S01);
    u21.h = __floats2half2_rn(S02, S11);
    u22.h = __floats2half2_rn(S12, S22);
    uc.h  = __floats2half2_rn(color[g], 0.f);

    float mx = mu[g*3+0], my = mu[g*3+1], mz = mu[g*3+2];
    table[(size_t)g*2+0] = make_float4(mx, my, mz, u01.f);
    table[(size_t)g*2+1] = make_float4(u21.f, u22.f, uc.f, 0.f);
}

// per-lane task weight (R6 parity scheme: even lanes own point A, odd own B)
__device__ __forceinline__ void task_wwc(
    float4 vA, float4 vB, int parity,
    float cx, float cy, float cz,
    float pa, float pb, float pc, float pe, float pf, float pi,
    float& w_out, float& wc_out)
{
    float4 oA, oB;
    oA.x = __shfl_xor(vA.x, 1); oA.y = __shfl_xor(vA.y, 1);
    oA.z = __shfl_xor(vA.z, 1); oA.w = __shfl_xor(vA.w, 1);
    oB.x = __shfl_xor(vB.x, 1); oB.y = __shfl_xor(vB.y, 1);
    oB.z = __shfl_xor(vB.z, 1); oB.w = __shfl_xor(vB.w, 1);
    float4 r0 = parity ? oB : vA;
    float4 r1 = parity ? vB : oA;

    H2F u01, u21, u22, uc;
    u01.f = r0.w; u21.f = r1.x; u22.f = r1.y; uc.f = r1.z;
    float2 s01 = __half22float2(u01.h);
    float2 s21 = __half22float2(u21.h);
    float2 s22 = __half22float2(u22.h);
    float  col = __half22float2(uc.h).x;

    float a = s01.x + pa, b = s01.y + pb, c = s21.x + pc;
    float e = s21.y + pe, f = s22.x + pf, i = s22.y + pi;
    float vx = cx - r0.x, vy = cy - r0.y, vz = cz - r0.z;

    float ei_fh = e*i - f*f;
    float det = a*ei_fh - b*(b*i - f*c) + c*(b*f - e*c);
    float inv_det = 1.0f / (det + EPS);
    float i00 = ei_fh * inv_det;
    float i01 = (c*f - b*i) * inv_det;
    float i02 = (b*f - c*e) * inv_det;
    float i11 = (a*i - c*c) * inv_det;
    float i12 = (c*b - a*f) * inv_det;
    float i22 = (a*e - b*b) * inv_det;

    float q0 = i00*vx + i01*vy + i02*vz;
    float q1 = i01*vx + i11*vy + i12*vz;
    float q2 = i02*vx + i12*vy + i22*vz;
    float inner = vx*q0 + vy*q1 + vz*q2;

    float w = __expf(-0.5f * inner);
    w_out  = w;
    wc_out = w * col;
}

// ---------------------------------------------------------------------------
// Persistent pipelined kernel: each wave grid-strides over point-pairs.
// Iteration k: issue gathers(k+1) (idx already resident), point-data(k+1),
// idx(k+2) -- THEN compute pair k. Every wave keeps ~64 table lines in
// flight continuously; gathers get a full compute-iteration of latency cover.
// ---------------------------------------------------------------------------
__global__ __launch_bounds__(256, 6) void gsvr_pipe(
    const float* __restrict__ coords,
    const float* __restrict__ psf,
    const int*   __restrict__ idcs,
    const float4* __restrict__ table,
    float* __restrict__ out, int n_pts, int n_pairs, int n_waves)
{
    int gtid   = blockIdx.x * blockDim.x + threadIdx.x;
    int wid    = gtid >> 6;
    int lane   = gtid & 63;
    int parity = lane & 1;
    int t      = lane >> 1;
    if (wid >= n_pairs) return;

    int k = wid;

    // ---- prologue: stage pair k fully, idx for pair k+stride ----
    int pA = 2*k, pB = min(2*k+1, n_pts-1);
    int gA = __builtin_nontemporal_load(idcs + (size_t)pA*32 + t);
    int gB = __builtin_nontemporal_load(idcs + (size_t)pB*32 + t);
    float4 vA = table[(size_t)gA*2 + parity];
    float4 vB = table[(size_t)gB*2 + parity];
    int pm = parity ? pB : pA;
    float cx = __builtin_nontemporal_load(coords + (size_t)pm*3+0);
    float cy = __builtin_nontemporal_load(coords + (size_t)pm*3+1);
    float cz = __builtin_nontemporal_load(coords + (size_t)pm*3+2);
    const float* sp = psf + (size_t)pm*9;
    float pa = __builtin_nontemporal_load(sp+0);
    float pb = __builtin_nontemporal_load(sp+1);
    float pc = __builtin_nontemporal_load(sp+2);
    float pe = __builtin_nontemporal_load(sp+4);
    float pf = __builtin_nontemporal_load(sp+5);
    float pi = __builtin_nontemporal_load(sp+8);

    int kN = k + n_waves;
    int gA_n = 0, gB_n = 0;
    if (kN < n_pairs) {
        gA_n = __builtin_nontemporal_load(idcs + (size_t)(2*kN)*32 + t);
        gB_n = __builtin_nontemporal_load(idcs + (size_t)min(2*kN+1, n_pts-1)*32 + t);
    }

    for (;;) {
        bool hasNext = (kN < n_pairs);
        float4 vA2, vB2;
        float cx2, cy2, cz2, pa2, pb2, pc2, pe2, pf2, pi2;
        int gA_nn = 0, gB_nn = 0;
        if (hasNext) {
            // gathers for pair kN (idx already resident -> issue immediately)
            vA2 = table[(size_t)gA_n*2 + parity];
            vB2 = table[(size_t)gB_n*2 + parity];
            int qA = 2*kN, qB = min(2*kN+1, n_pts-1);
            int qm = parity ? qB : qA;
            cx2 = __builtin_nontemporal_load(coords + (size_t)qm*3+0);
            cy2 = __builtin_nontemporal_load(coords + (size_t)qm*3+1);
            cz2 = __builtin_nontemporal_load(coords + (size_t)qm*3+2);
            const float* sq = psf + (size_t)qm*9;
            pa2 = __builtin_nontemporal_load(sq+0);
            pb2 = __builtin_nontemporal_load(sq+1);
            pc2 = __builtin_nontemporal_load(sq+2);
            pe2 = __builtin_nontemporal_load(sq+4);
            pf2 = __builtin_nontemporal_load(sq+5);
            pi2 = __builtin_nontemporal_load(sq+8);
            int kNN = kN + n_waves;
            if (kNN < n_pairs) {
                gA_nn = __builtin_nontemporal_load(idcs + (size_t)(2*kNN)*32 + t);
                gB_nn = __builtin_nontemporal_load(idcs + (size_t)min(2*kNN+1, n_pts-1)*32 + t);
            }
        }

        // ---- compute pair k (gathers issued one full iteration ago) ----
        float w, wc;
        task_wwc(vA, vB, parity, cx, cy, cz, pa, pb, pc, pe, pf, pi, w, wc);
        #pragma unroll
        for (int m = 32; m >= 2; m >>= 1) {
            w  += __shfl_xor(w,  m);
            wc += __shfl_xor(wc, m);
        }
        int po = 2*k + lane;
        if (lane < 2 && po < n_pts)
            __builtin_nontemporal_store(wc / (w + DELTA), out + po);

        if (!hasNext) break;
        // ---- rotate double buffer ----
        vA = vA2; vB = vB2;
        cx = cx2; cy = cy2; cz = cz2;
        pa = pa2; pb = pb2; pc = pc2; pe = pe2; pf = pf2; pi = pi2;
        gA_n = gA_nn; gB_n = gB_nn;
        k = kN; kN = k + n_waves;
    }
}

// ---------------------------------------------------------------------------
// Fallback (ws too small): lane-per-task, compute Sigma inline, all fp32.
// ---------------------------------------------------------------------------
__global__ __launch_bounds__(256) void gsvr_fallback(
    const float* __restrict__ coords,
    const float* __restrict__ psf,
    const int*   __restrict__ idcs,
    const float* __restrict__ mu,
    const float* __restrict__ scaling,
    const float* __restrict__ rot,
    const float* __restrict__ color,
    float* __restrict__ out, int n_pts)
{
    int tid = blockIdx.x * blockDim.x + threadIdx.x;
    int p  = tid >> 5;
    int kk = tid & 31;
    if (p >= n_pts) return;

    float cx = coords[p*3+0], cy = coords[p*3+1], cz = coords[p*3+2];
    const float* sp = psf + (size_t)p*9;
    float pa = sp[0], pb = sp[1], pc = sp[2], pe = sp[4], pf = sp[5], pi = sp[8];

    int g = idcs[p*32 + kk];
    float qw = rot[g*4+0], qx = rot[g*4+1], qy = rot[g*4+2], qz = rot[g*4+3];
    float inv_norm = rsqrtf(qw*qw + qx*qx + qy*qy + qz*qz + EPS);
    qw *= inv_norm; qx *= inv_norm; qy *= inv_norm; qz *= inv_norm;
    float x2 = qx*qx, y2 = qy*qy, z2 = qz*qz;
    float xy = qx*qy, xz = qx*qz, yz = qy*qz;
    float wx = qw*qx, wy = qw*qy, wz = qw*qz;
    float R00 = 1.f - 2.f*(y2 + z2), R01 = 2.f*(xy - wz),       R02 = 2.f*(xz + wy);
    float R10 = 2.f*(xy + wz),       R11 = 1.f - 2.f*(x2 + z2), R12 = 2.f*(yz - wx);
    float R20 = 2.f*(xz - wy),       R21 = 2.f*(yz + wx),       R22 = 1.f - 2.f*(x2 + y2);
    float s0 = scaling[g*3+0], s1 = scaling[g*3+1], s2 = scaling[g*3+2];
    float dd0 = s0*s0, dd1 = s1*s1, dd2 = s2*s2;
    float S00 = R00*R00*dd0 + R01*R01*dd1 + R02*R02*dd2;
    float S01 = R00*R10*dd0 + R01*R11*dd1 + R02*R12*dd2;
    float S02 = R00*R20*dd0 + R01*R21*dd1 + R02*R22*dd2;
    float S11 = R10*R10*dd0 + R11*R11*dd1 + R12*R12*dd2;
    float S12 = R10*R20*dd0 + R11*R21*dd1 + R12*R22*dd2;
    float S22 = R20*R20*dd0 + R21*R21*dd1 + R22*R22*dd2;

    float a = S00 + pa, b = S01 + pb, c = S02 + pc;
    float e = S11 + pe, f = S12 + pf, i = S22 + pi;
    float vx = cx - mu[g*3+0], vy = cy - mu[g*3+1], vz = cz - mu[g*3+2];

    float ei_fh = e*i - f*f;
    float det = a*ei_fh - b*(b*i - f*c) + c*(b*f - e*c);
    float inv_det = 1.0f / (det + EPS);
    float i00 = ei_fh * inv_det;
    float i01 = (c*f - b*i) * inv_det;
    float i02 = (b*f - c*e) * inv_det;
    float i11 = (a*i - c*c) * inv_det;
    float i12 = (c*b - a*f) * inv_det;
    float i22 = (a*e - b*b) * inv_det;

    float q0 = i00*vx + i01*vy + i02*vz;
    float q1 = i01*vx + i11*vy + i12*vz;
    float q2 = i02*vx + i12*vy + i22*vz;
    float inner = vx*q0 + vy*q1 + vz*q2;

    float w  = __expf(-0.5f * inner);
    float wc = w * color[g];

    #pragma unroll
    for (int m = 16; m >= 1; m >>= 1) {
        w  += __shfl_xor(w,  m);
        wc += __shfl_xor(wc, m);
    }
    if (kk == 0) out[p] = wc / (w + DELTA);
}

extern "C" void kernel_launch(void* const* d_in, const int* in_sizes, int n_in,
                              void* d_out, int out_size, void* d_ws, size_t ws_size,
                              hipStream_t stream)
{
    const float* coords  = (const float*)d_in[0];
    const float* psf     = (const float*)d_in[1];
    const float* mu      = (const float*)d_in[2];
    const float* scaling = (const float*)d_in[3];
    const float* rot     = (const float*)d_in[4];
    const float* color   = (const float*)d_in[5];
    const int*   idcs    = (const int*)d_in[6];
    float* out = (float*)d_out;

    int n_pts = in_sizes[0] / 3;
    int G     = in_sizes[5];

    size_t need = (size_t)G * 8 * sizeof(float);   // 32 B per gaussian

    if (ws_size >= need) {
        float4* table = (float4*)d_ws;
        precompute_gauss<<<(G + 255) / 256, 256, 0, stream>>>(mu, scaling, rot, color, table, G);
        int n_pairs = (n_pts + 1) / 2;
        int blocks  = 2048;                 // 8192 persistent waves
        int n_waves = blocks * (256 / 64);
        if (n_waves > n_pairs) n_waves = n_pairs;   // degenerate small-N case
        gsvr_pipe<<<blocks, 256, 0, stream>>>(
            coords, psf, idcs, table, out, n_pts, n_pairs, n_waves);
    } else {
        int threads = n_pts * 32;
        gsvr_fallback<<<(threads + 255) / 256, 256, 0, stream>>>(
            coords, psf, idcs, mu, scaling, rot, color, out, n_pts);
    }
}

// Round 8
// 44.404 us; speedup vs baseline: 1.1830x; 1.1830x over previous
//
#include <hip/hip_runtime.h>
#include <hip/hip_fp16.h>

#define DELTA 0.05f
#define EPS 1e-8f

union H2F { __half2 h; float f; };

// ---------------------------------------------------------------------------
// Precompute per-gaussian packed 32-B record (two float4s, 32-B aligned, so
// both halves always share one 64-B line):
//   r0 = [mux f32, muy f32, muz f32, (S00,S01) half2]
//   r1 = [(S02,S11) half2, (S12,S22) half2, (color,0) half2, pad]
// Sigma = R diag(s^2) R^T  (scale_scale = 1)
// ---------------------------------------------------------------------------
__global__ __launch_bounds__(256) void precompute_gauss(
    const float* __restrict__ mu,
    const float* __restrict__ scaling,
    const float* __restrict__ rot,
    const float* __restrict__ color,
    float4* __restrict__ table, int G)
{
    int g = blockIdx.x * blockDim.x + threadIdx.x;
    if (g >= G) return;
    float qw = rot[g*4+0], qx = rot[g*4+1], qy = rot[g*4+2], qz = rot[g*4+3];
    float inv_norm = rsqrtf(qw*qw + qx*qx + qy*qy + qz*qz + EPS);
    qw *= inv_norm; qx *= inv_norm; qy *= inv_norm; qz *= inv_norm;
    float x2 = qx*qx, y2 = qy*qy, z2 = qz*qz;
    float xy = qx*qy, xz = qx*qz, yz = qy*qz;
    float wx = qw*qx, wy = qw*qy, wz = qw*qz;
    float R00 = 1.f - 2.f*(y2 + z2), R01 = 2.f*(xy - wz),       R02 = 2.f*(xz + wy);
    float R10 = 2.f*(xy + wz),       R11 = 1.f - 2.f*(x2 + z2), R12 = 2.f*(yz - wx);
    float R20 = 2.f*(xz - wy),       R21 = 2.f*(yz + wx),       R22 = 1.f - 2.f*(x2 + y2);
    float s0 = scaling[g*3+0], s1 = scaling[g*3+1], s2 = scaling[g*3+2];
    float d0 = s0*s0, d1 = s1*s1, d2 = s2*s2;
    float S00 = R00*R00*d0 + R01*R01*d1 + R02*R02*d2;
    float S01 = R00*R10*d0 + R01*R11*d1 + R02*R12*d2;
    float S02 = R00*R20*d0 + R01*R21*d1 + R02*R22*d2;
    float S11 = R10*R10*d0 + R11*R11*d1 + R12*R12*d2;
    float S12 = R10*R20*d0 + R11*R21*d1 + R12*R22*d2;
    float S22 = R20*R20*d0 + R21*R21*d1 + R22*R22*d2;

    H2F u01, u21, u22, uc;
    u01.h = __floats2half2_rn(S00, S01);
    u21.h = __floats2half2_rn(S02, S11);
    u22.h = __floats2half2_rn(S12, S22);
    uc.h  = __floats2half2_rn(color[g], 0.f);

    float mx = mu[g*3+0], my = mu[g*3+1], mz = mu[g*3+2];
    table[(size_t)g*2+0] = make_float4(mx, my, mz, u01.f);
    table[(size_t)g*2+1] = make_float4(u21.f, u22.f, uc.f, 0.f);
}

// ---------------------------------------------------------------------------
// Main kernel: exact round-6 structure (best known: ~41 us main), with ONE
// change: the two table gathers bypass L1 via `sc0` (serve from L2, no L1
// line allocation). Tests whether the ~6.4 cy/miss wall is the L1 fill path.
// One wave per TWO points; lane 2t+h gathers half h of task-t's record for
// both points (pair-merged into 1 line transaction/task); even lanes own
// point A, odd own point B; one shfl_xor(.,1) round completes records;
// parity-preserving butterfly reduces.
// ---------------------------------------------------------------------------
__global__ __launch_bounds__(256) void gsvr_dual(
    const float* __restrict__ coords,
    const float* __restrict__ psf,
    const int*   __restrict__ idcs,
    const float4* __restrict__ table,
    float* __restrict__ out, int n_pts)
{
    int tid    = blockIdx.x * blockDim.x + threadIdx.x;
    int waveId = tid >> 6;
    int lane   = tid & 63;
    int pA     = waveId * 2;
    if (pA >= n_pts) return;
    int pB     = min(pA + 1, n_pts - 1);
    int parity = lane & 1;
    int t      = lane >> 1;

    int gA = __builtin_nontemporal_load(idcs + (size_t)pA*32 + t);
    int gB = __builtin_nontemporal_load(idcs + (size_t)pB*32 + t);

    // per-lane point data (even lanes -> A, odd -> B); issued first so they
    // are covered by the gather drain below
    int pm = parity ? pB : pA;
    float cx = __builtin_nontemporal_load(coords + (size_t)pm*3+0);
    float cy = __builtin_nontemporal_load(coords + (size_t)pm*3+1);
    float cz = __builtin_nontemporal_load(coords + (size_t)pm*3+2);
    const float* sp = psf + (size_t)pm*9;
    float pa = __builtin_nontemporal_load(sp+0);
    float pb = __builtin_nontemporal_load(sp+1);
    float pc = __builtin_nontemporal_load(sp+2);
    float pe = __builtin_nontemporal_load(sp+4);
    float pf = __builtin_nontemporal_load(sp+5);
    float pi = __builtin_nontemporal_load(sp+8);

    // pair-coalesced gathers, L1-BYPASS (sc0): one 16-B load per lane per
    // point; data is consumed only after the in-asm vmcnt(0), and the
    // outputs are defined by this asm so nothing can read them earlier.
    const float4* addrA = table + ((size_t)gA*2 + parity);
    const float4* addrB = table + ((size_t)gB*2 + parity);
    float4 vA, vB;
    asm volatile(
        "global_load_dwordx4 %0, %2, off sc0\n\t"
        "global_load_dwordx4 %1, %3, off sc0\n\t"
        "s_waitcnt vmcnt(0)"
        : "=&v"(vA), "=&v"(vB)
        : "v"(addrA), "v"(addrB)
        : "memory");

    // complete each lane's record with one xor-1 exchange round
    float4 oA, oB;
    oA.x = __shfl_xor(vA.x, 1); oA.y = __shfl_xor(vA.y, 1);
    oA.z = __shfl_xor(vA.z, 1); oA.w = __shfl_xor(vA.w, 1);
    oB.x = __shfl_xor(vB.x, 1); oB.y = __shfl_xor(vB.y, 1);
    oB.z = __shfl_xor(vB.z, 1); oB.w = __shfl_xor(vB.w, 1);
    float4 r0 = parity ? oB : vA;
    float4 r1 = parity ? vB : oA;

    H2F u01, u21, u22, uc;
    u01.f = r0.w; u21.f = r1.x; u22.f = r1.y; uc.f = r1.z;
    float2 s01 = __half22float2(u01.h);
    float2 s21 = __half22float2(u21.h);
    float2 s22 = __half22float2(u22.h);
    float  col = __half22float2(uc.h).x;

    float a = s01.x + pa, b = s01.y + pb, c = s21.x + pc;
    float e = s21.y + pe, f = s22.x + pf, i = s22.y + pi;
    float vx = cx - r0.x, vy = cy - r0.y, vz = cz - r0.z;

    float ei_fh = e*i - f*f;
    float det = a*ei_fh - b*(b*i - f*c) + c*(b*f - e*c);
    float inv_det = 1.0f / (det + EPS);
    float i00 = ei_fh * inv_det;
    float i01 = (c*f - b*i) * inv_det;
    float i02 = (b*f - c*e) * inv_det;
    float i11 = (a*i - c*c) * inv_det;
    float i12 = (c*b - a*f) * inv_det;
    float i22 = (a*e - b*b) * inv_det;

    float q0 = i00*vx + i01*vy + i02*vz;
    float q1 = i01*vx + i11*vy + i12*vz;
    float q2 = i02*vx + i12*vy + i22*vz;
    float inner = vx*q0 + vy*q1 + vz*q2;

    float w  = __expf(-0.5f * inner);
    float wc = w * col;

    // parity-preserving butterfly: even masks only
    #pragma unroll
    for (int m = 32; m >= 2; m >>= 1) {
        w  += __shfl_xor(w,  m);
        wc += __shfl_xor(wc, m);
    }
    int po = pA + lane;
    if (lane < 2 && po < n_pts)
        __builtin_nontemporal_store(wc / (w + DELTA), out + po);
}

// ---------------------------------------------------------------------------
// Fallback (ws too small): lane-per-task, compute Sigma inline, all fp32.
// ---------------------------------------------------------------------------
__global__ __launch_bounds__(256) void gsvr_fallback(
    const float* __restrict__ coords,
    const float* __restrict__ psf,
    const int*   __restrict__ idcs,
    const float* __restrict__ mu,
    const float* __restrict__ scaling,
    const float* __restrict__ rot,
    const float* __restrict__ color,
    float* __restrict__ out, int n_pts)
{
    int tid = blockIdx.x * blockDim.x + threadIdx.x;
    int p  = tid >> 5;
    int kk = tid & 31;
    if (p >= n_pts) return;

    float cx = coords[p*3+0], cy = coords[p*3+1], cz = coords[p*3+2];
    const float* sp = psf + (size_t)p*9;
    float pa = sp[0], pb = sp[1], pc = sp[2], pe = sp[4], pf = sp[5], pi = sp[8];

    int g = idcs[p*32 + kk];
    float qw = rot[g*4+0], qx = rot[g*4+1], qy = rot[g*4+2], qz = rot[g*4+3];
    float inv_norm = rsqrtf(qw*qw + qx*qx + qy*qy + qz*qz + EPS);
    qw *= inv_norm; qx *= inv_norm; qy *= inv_norm; qz *= inv_norm;
    float x2 = qx*qx, y2 = qy*qy, z2 = qz*qz;
    float xy = qx*qy, xz = qx*qz, yz = qy*qz;
    float wx = qw*qx, wy = qw*qy, wz = qw*qz;
    float R00 = 1.f - 2.f*(y2 + z2), R01 = 2.f*(xy - wz),       R02 = 2.f*(xz + wy);
    float R10 = 2.f*(xy + wz),       R11 = 1.f - 2.f*(x2 + z2), R12 = 2.f*(yz - wx);
    float R20 = 2.f*(xz - wy),       R21 = 2.f*(yz + wx),       R22 = 1.f - 2.f*(x2 + y2);
    float s0 = scaling[g*3+0], s1 = scaling[g*3+1], s2 = scaling[g*3+2];
    float dd0 = s0*s0, dd1 = s1*s1, dd2 = s2*s2;
    float S00 = R00*R00*dd0 + R01*R01*dd1 + R02*R02*dd2;
    float S01 = R00*R10*dd0 + R01*R11*dd1 + R02*R12*dd2;
    float S02 = R00*R20*dd0 + R01*R21*dd1 + R02*R22*dd2;
    float S11 = R10*R10*dd0 + R11*R11*dd1 + R12*R12*dd2;
    float S12 = R10*R20*dd0 + R11*R21*dd1 + R12*R22*dd2;
    float S22 = R20*R20*dd0 + R21*R21*dd1 + R22*R22*dd2;

    float a = S00 + pa, b = S01 + pb, c = S02 + pc;
    float e = S11 + pe, f = S12 + pf, i = S22 + pi;
    float vx = cx - mu[g*3+0], vy = cy - mu[g*3+1], vz = cz - mu[g*3+2];

    float ei_fh = e*i - f*f;
    float det = a*ei_fh - b*(b*i - f*c) + c*(b*f - e*c);
    float inv_det = 1.0f / (det + EPS);
    float i00 = ei_fh * inv_det;
    float i01 = (c*f - b*i) * inv_det;
    float i02 = (b*f - c*e) * inv_det;
    float i11 = (a*i - c*c) * inv_det;
    float i12 = (c*b - a*f) * inv_det;
    float i22 = (a*e - b*b) * inv_det;

    float q0 = i00*vx + i01*vy + i02*vz;
    float q1 = i01*vx + i11*vy + i12*vz;
    float q2 = i02*vx + i12*vy + i22*vz;
    float inner = vx*q0 + vy*q1 + vz*q2;

    float w  = __expf(-0.5f * inner);
    float wc = w * color[g];

    #pragma unroll
    for (int m = 16; m >= 1; m >>= 1) {
        w  += __shfl_xor(w,  m);
        wc += __shfl_xor(wc, m);
    }
    if (kk == 0) out[p] = wc / (w + DELTA);
}

extern "C" void kernel_launch(void* const* d_in, const int* in_sizes, int n_in,
                              void* d_out, int out_size, void* d_ws, size_t ws_size,
                              hipStream_t stream)
{
    const float* coords  = (const float*)d_in[0];
    const float* psf     = (const float*)d_in[1];
    const float* mu      = (const float*)d_in[2];
    const float* scaling = (const float*)d_in[3];
    const float* rot     = (const float*)d_in[4];
    const float* color   = (const float*)d_in[5];
    const int*   idcs    = (const int*)d_in[6];
    float* out = (float*)d_out;

    int n_pts = in_sizes[0] / 3;
    int G     = in_sizes[5];

    size_t need = (size_t)G * 8 * sizeof(float);   // 32 B per gaussian

    if (ws_size >= need) {
        float4* table = (float4*)d_ws;
        precompute_gauss<<<(G + 255) / 256, 256, 0, stream>>>(mu, scaling, rot, color, table, G);
        long long waves   = ((long long)n_pts + 1) / 2;
        long long threads = waves * 64;
        gsvr_dual<<<(int)((threads + 255) / 256), 256, 0, stream>>>(
            coords, psf, idcs, table, out, n_pts);
    } else {
        int threads = n_pts * 32;
        gsvr_fallback<<<(threads + 255) / 256, 256, 0, stream>>>(
            coords, psf, idcs, mu, scaling, rot, color, out, n_pts);
    }
}